// Round 11
// baseline (187.845 us; speedup 1.0000x reference)
//
#include <hip/hip_runtime.h>
#include <hip/hip_bf16.h>

#define EPSBN 1e-5f

typedef short short8 __attribute__((ext_vector_type(8)));
typedef float f32x16 __attribute__((ext_vector_type(16)));

static __device__ __forceinline__ unsigned short f2u(float f){
  __hip_bfloat16 h = __float2bfloat16(f);
  union { __hip_bfloat16 h; unsigned short u; } c; c.h = h; return c.u;
}

// ---- workspace layout (bytes) ----
#define WS_G     2048
#define WS_S     7168
#define WS_T     8192
#define WS_AGGB  16384      // 147456 bf16  [b][cc2][s9][o32][ci32]
#define WS_XUP   327680     // 33554432 bf16 [b][h16(4)][r256][c256][ci16]  (plane = 1<<20 halfwords)

#define XIN_S 820   // per-ci-plane float stride; 820%32=20 -> ci2 lanes (planes 2ci2)
                    // land on banks {0,8,16,24}: conflict-free column reads.

// ------- K1: bilinear x2 upsample -> bf16 planes, GAP fused -------
// 8-ci blocks. grid 2048 = b(8) x g8(8 ci-octets) x strip(32 of 8 rows).
// LDS 26.2KB -> 6 blocks/CU. XCD-chunked swizzle: b == xcd so xup writes land
// in the L2 slice k_conv (b==xcd) reads.
__global__ __launch_bounds__(256) void k_up(const float* __restrict__ x,
                                            unsigned int* __restrict__ xup32,
                                            float* __restrict__ g)
{
  __shared__ float xin[8*XIN_S];   // [ci8][ir6][j136: 128 data + 8 zero pad]
  __shared__ float w[128];
  int tid = threadIdx.x;
  int bi  = blockIdx.x;
  int sw  = ((bi & 7) << 8) + (bi >> 3);   // nwg=2048 bijective; b == xcd
  int b   = sw >> 8, rest = sw & 255;
  int g8  = rest >> 5, strip = rest & 31;
  int r0 = strip * 8;
  int i0b = (int)((float)r0 * (127.0f/255.0f));

  if (tid < 128){
    int i = tid;
    float s = 0.f;
    int rstart = max(0, (int)floorf((float)(i-1)*(255.0f/127.0f)));
    #pragma unroll
    for (int k = 0; k < 8; ++k){
      int r = rstart + k;
      if (r <= 255){
        float pos = (float)r * (127.0f/255.0f);
        int i0 = (int)pos; float fr = pos - (float)i0; int i1 = min(i0+1,127);
        if (i0 == i) s += 1.0f - fr;
        if (i1 == i) s += fr;
      }
    }
    w[i] = s;
  }
  // loads: 8 ci x 6 rows x 128 cols = 1536 float4, 6 per thread
  #pragma unroll
  for (int k = 0; k < 6; ++k){
    int e4 = tid + (k << 8);
    int j4 = e4 & 31, ci = (e4 >> 5) & 7, ir = e4 >> 8;
    int row = min(i0b + ir, 127);
    *(float4*)&xin[ci*XIN_S + ir*136 + j4*4] =
      *(const float4*)&x[(((size_t)(b*64 + g8*8 + ci)) << 14) + (row << 7) + j4*4];
  }
  // zero pad cols 128..135 (j0+1 clamp-free)
  for (int e2 = tid; e2 < 384; e2 += 256){
    int k = e2 & 7, t8 = e2 >> 3;
    int ir = t8 % 6, ci = t8 / 6;
    xin[ci*XIN_S + ir*136 + 128 + k] = 0.f;
  }
  __syncthreads();

  // ---- GAP partial: source rows 4*strip..4*strip+3 (disjoint across strips) ----
  {
    int ci_l = tid >> 5, kk = tid & 31;    // 8 ci x 32 lanes, 4 cols each
    float s = 0.f;
    const float* base = &xin[ci_l*XIN_S];
    #pragma unroll
    for (int row = 0; row < 4; ++row){
      int grow = 4*strip + row;
      int ir = grow - i0b;                 // in [0,6) by construction
      const float* rp = base + ir*136 + kk*4;
      float ss = 0.f;
      #pragma unroll
      for (int j = 0; j < 4; ++j) ss += rp[j]*w[kk*4+j];
      s += w[grow]*ss;
    }
    s += __shfl_down(s, 16, 32);
    s += __shfl_down(s, 8, 32);
    s += __shfl_down(s, 4, 32);
    s += __shfl_down(s, 2, 32);
    s += __shfl_down(s, 1, 32);
    if (kk == 0) atomicAdd(&g[b*64 + g8*8 + ci_l], s*(1.0f/65536.0f));
  }

  // ---- interp: horizontal-first, rolling 2-row register cache ----
  int ci2 = tid & 3, cbase = tid >> 2;     // cbase 0..63; c = cbase + 64*jj
  const float* b0p = &xin[(ci2*2+0)*XIN_S];
  const float* b1p = &xin[(ci2*2+1)*XIN_S];
  size_t plane32 = ((size_t)(b*4 + (g8 >> 1))) << 19;
  int slot = (g8 & 1)*4 + ci2;             // dword slot within [ci16] (8 dwords)

  #pragma unroll
  for (int jj = 0; jj < 4; ++jj){
    int c = cbase + 64*jj;
    float pos = (float)c * (127.0f/255.0f);
    int j0 = (int)pos; float ww = pos - (float)j0;

    int irA = 0;
    float A0, B0, A1, B1;
    {
      float x0 = b0p[j0],     x1 = b0p[j0+1];     A0 = x0 + (x1-x0)*ww;
      float y0 = b1p[j0],     y1 = b1p[j0+1];     A1 = y0 + (y1-y0)*ww;
      float x2 = b0p[136+j0], x3 = b0p[136+j0+1]; B0 = x2 + (x3-x2)*ww;
      float y2 = b1p[136+j0], y3 = b1p[136+j0+1]; B1 = y2 + (y3-y2)*ww;
    }
    #pragma unroll
    for (int rr = 0; rr < 8; ++rr){
      int r = r0 + rr;
      float posr = (float)r * (127.0f/255.0f);
      int i0 = (int)posr; float wh = posr - (float)i0;
      int ir0 = i0 - i0b;
      if (ir0 > irA){                 // wave-uniform branch (all threads share strip)
        A0 = B0; A1 = B1;
        int irB = ir0 + 1;            // <= 5 by construction
        float x0 = b0p[irB*136+j0], x1 = b0p[irB*136+j0+1]; B0 = x0 + (x1-x0)*ww;
        float y0 = b1p[irB*136+j0], y1 = b1p[irB*136+j0+1]; B1 = y0 + (y1-y0)*ww;
        irA = ir0;
      }
      float r0v = A0 + (B0-A0)*wh;
      float r1v = A1 + (B1-A1)*wh;
      unsigned pack = (unsigned)f2u(r0v) | (((unsigned)f2u(r1v)) << 16);
      xup32[plane32 + (size_t)(r*256 + c)*8 + slot] = pack;
    }
  }
}

// ------- K2: attention MLP (redundant per block) + aggregated bf16 filters -------
__global__ __launch_bounds__(256) void k_aggw(const float* __restrict__ g,
                      const float* __restrict__ fc_w,
                      const float* __restrict__ bga, const float* __restrict__ bba,
                      const float* __restrict__ bma, const float* __restrict__ bva,
                      const float* __restrict__ ch_w, const float* __restrict__ ch_b,
                      const float* __restrict__ fil_w, const float* __restrict__ fil_b,
                      const float* __restrict__ sp_w, const float* __restrict__ sp_b,
                      const float* __restrict__ k_w, const float* __restrict__ k_b,
                      const float* __restrict__ bn_g, const float* __restrict__ bn_b,
                      const float* __restrict__ bn_m, const float* __restrict__ bn_v,
                      const float* __restrict__ weight,
                      unsigned short* __restrict__ aggb,
                      float* __restrict__ sS, float* __restrict__ tT)
{
  __shared__ float h[8][16];
  int tid = threadIdx.x;
  if (tid < 128){
    int b = tid >> 4, a = tid & 15;
    float acc = 0.f;
    for (int c = 0; c < 64; ++c) acc += g[b*64+c] * fc_w[a*64+c];
    float v = (acc - bma[a]) * rsqrtf(bva[a] + EPSBN) * bga[a] + bba[a];
    h[b][a] = fmaxf(v, 0.f);
  }
  __syncthreads();

  int idx = blockIdx.x*256 + tid;
  int ci_l = idx & 31;
  int o    = (idx >> 5) & 31;
  int s    = (idx >> 10) % 9;
  int t2   = (idx >> 10) / 9;
  int cc   = t2 & 1, b = t2 >> 1;
  int ci   = cc*32 + ci_l;

  const float* hb = h[b];
  float zc = ch_b[ci], zs = sp_b[s];
  float z0 = k_b[0],  z1 = k_b[1];
  #pragma unroll
  for (int a = 0; a < 16; ++a){
    float hv = hb[a];
    zc += hv*ch_w[ci*16+a];
    zs += hv*sp_w[s*16+a];
    z0 += hv*k_w[a];
    z1 += hv*k_w[16+a];
  }
  float chv = 1.f/(1.f+expf(-zc));
  float spv = 1.f/(1.f+expf(-zs));
  float m = fmaxf(z0,z1);
  float e0 = expf(z0-m), e1 = expf(z1-m), inv = 1.f/(e0+e1);
  float ka0 = e0*inv, ka1 = e1*inv;
  float w0 = weight[(o*64+ci)*9+s];
  float w1 = weight[((32+o)*64+ci)*9+s];
  aggb[idx] = f2u(chv*spv*(ka0*w0 + ka1*w1));

  if (blockIdx.x == 0){
    int bb = tid >> 5, oo = tid & 31;
    float z = fil_b[oo];
    #pragma unroll
    for (int a = 0; a < 16; ++a) z += h[bb][a]*fil_w[oo*16+a];
    float f = 1.f/(1.f+expf(-z));
    float invs = rsqrtf(bn_v[oo] + EPSBN);
    sS[tid] = f * bn_g[oo] * invs;
    if (bb == 0) tT[oo] = bn_b[oo] - bn_m[oo]*bn_g[oo]*invs;
  }
}

// -------- K3: MFMA implicit-GEMM conv + BN + GELU --------
// R9 skeleton (best: 47.3us). This round:
// (1) XOR-unit-swizzled xt: row = 18 cols x 32hw + 8hw pad (ROWHW=584 -> rows
//     shift banks by +4), 16B units permuted pu = u ^ ((col>>1)&3). Hand-checked:
//     wave b128 reads AND staging writes hit every bank-group exactly 8x = the
//     1024B/128B minimum. LDS 25.9 -> 21.0KB -> 7 blocks/CU. All 16B-aligned.
// (2) epilogue: exact erff -> sigmoid-form tanh-GELU (~8 VALU vs ~20; max dev
//     from exact ~5e-4, threshold 5.5e-3).
#define ROWHW 584   // 18*32 + 8 hw

__global__ __launch_bounds__(256) void k_conv(const unsigned short* __restrict__ xup,
                                              const unsigned short* __restrict__ aggb,
                                              const float* __restrict__ sS,
                                              const float* __restrict__ tT,
                                              float* __restrict__ out)
{
  __shared__ unsigned short xt[18*ROWHW];   // 21024 B
  __shared__ float sSs[32], tTs[32];

  int tid = threadIdx.x;
  int bi  = blockIdx.x;
  int sw  = ((bi & 7) << 8) + (bi >> 3);   // nwg=2048 -> xcd*256 + idx (bijective; b == xcd)
  int b   = sw >> 8, t = sw & 255;
  int p0  = (t >> 4) * 16, q0 = (t & 15) * 16;
  int lane = tid & 63, wv = tid >> 6;
  if (tid < 32){ sSs[tid] = sS[b*32+tid]; tTs[tid] = tT[tid]; }

  f32x16 acc[2];
  #pragma unroll
  for (int i = 0; i < 16; ++i){ acc[0][i] = 0.f; acc[1][i] = 0.f; }

  int n  = lane & 31;
  int kq = lane >> 5;
  int lr0 = 2*(2*wv + 0) + (n >> 4);
  int lr1 = 2*(2*wv + 1) + (n >> 4);
  int qb  = n & 15;

  // per-kx swizzled unit offsets (hw), computed once: col = qb+kx
  int off0k[3], off1k[3];
  #pragma unroll
  for (int kx = 0; kx < 3; ++kx){
    int key = ((qb + kx) >> 1) & 3;
    int o0 = (kq ^ key) * 8;
    off0k[kx] = o0;
    off1k[kx] = o0 ^ 16;
  }

  const unsigned short* xb0 = xup + (((size_t)(b*4 + 0)) << 20);
  const unsigned short* xb1 = xup + (((size_t)(b*4 + 2)) << 20);
  const short8 zero8 = {0,0,0,0,0,0,0,0};

  // ---- descriptors computed ONCE; pmo+ldso cached for the cc=1 restage ----
  int ldsoA[6], pmoA[6];
  unsigned vmask = 0;
  #pragma unroll
  for (int k = 0; k < 6; ++k){
    int e = tid + (k << 8); if (e >= 1296) e -= 1296;   // wrap dupes benign
    int rr = e / 72; int rem = e - rr*72;
    int qq = rem >> 2; int k2 = (rem >> 1) & 1; int kqe = rem & 1;
    int gr = p0 - 1 + rr, gq = q0 - 1 + qq;
    bool v = ((unsigned)gr < 256u) && ((unsigned)gq < 256u);
    int u  = k2*2 + kqe;
    int ldso = rr*ROWHW + qq*32 + ((u ^ ((qq >> 1) & 3)) << 3);
    int pmo  = (k2 << 20) + (gr*256 + gq)*16 + kqe*8;
    ldsoA[k] = ldso;
    pmoA[k]  = pmo;
    vmask |= (v ? 1u : 0u) << k;
    short8 vv = zero8;
    if (v) vv = *(const short8*)&xb0[pmo];
    *(short8*)&xt[ldso] = vv;
  }
  __syncthreads();

  // K-loop over a cc chunk; A-fragments pipelined 2 s-steps ahead
  auto kloop = [&](const unsigned short* ab){
    short8 a0 = *(const short8*)&ab[0];
    short8 a1 = *(const short8*)&ab[16];
    short8 b0 = *(const short8*)&ab[1024];
    short8 b1 = *(const short8*)&ab[1024+16];
    #pragma unroll
    for (int s = 0; s < 9; ++s){
      int sn = (s < 7) ? s+2 : 8;
      short8 c0 = *(const short8*)&ab[sn*1024];
      short8 c1 = *(const short8*)&ab[sn*1024+16];
      const int ky = s/3, kx = s%3;
      {
        const unsigned short* xrow = &xt[(lr0+ky)*ROWHW + (qb+kx)*32];
        short8 bv0 = *(const short8*)&xrow[off0k[kx]];
        short8 bv1 = *(const short8*)&xrow[off1k[kx]];
        acc[0] = __builtin_amdgcn_mfma_f32_32x32x16_bf16(a0, bv0, acc[0], 0, 0, 0);
        acc[0] = __builtin_amdgcn_mfma_f32_32x32x16_bf16(a1, bv1, acc[0], 0, 0, 0);
      }
      {
        const unsigned short* xrow = &xt[(lr1+ky)*ROWHW + (qb+kx)*32];
        short8 bv0 = *(const short8*)&xrow[off0k[kx]];
        short8 bv1 = *(const short8*)&xrow[off1k[kx]];
        acc[1] = __builtin_amdgcn_mfma_f32_32x32x16_bf16(a0, bv0, acc[1], 0, 0, 0);
        acc[1] = __builtin_amdgcn_mfma_f32_32x32x16_bf16(a1, bv1, acc[1], 0, 0, 0);
      }
      a0 = b0; a1 = b1; b0 = c0; b1 = c1;
    }
  };

  kloop(aggb + (size_t)(b*2+0)*9216 + n*32 + kq*8);
  __syncthreads();
  // stage cc=1 directly (cached descriptors; loads first, then LDS writes)
  {
    short8 v0 = zero8, v1 = zero8, v2 = zero8, v3 = zero8, v4 = zero8, v5 = zero8;
    if (vmask & 1u)  v0 = *(const short8*)&xb1[pmoA[0]];
    if (vmask & 2u)  v1 = *(const short8*)&xb1[pmoA[1]];
    if (vmask & 4u)  v2 = *(const short8*)&xb1[pmoA[2]];
    if (vmask & 8u)  v3 = *(const short8*)&xb1[pmoA[3]];
    if (vmask & 16u) v4 = *(const short8*)&xb1[pmoA[4]];
    if (vmask & 32u) v5 = *(const short8*)&xb1[pmoA[5]];
    *(short8*)&xt[ldsoA[0]] = v0;
    *(short8*)&xt[ldsoA[1]] = v1;
    *(short8*)&xt[ldsoA[2]] = v2;
    *(short8*)&xt[ldsoA[3]] = v3;
    *(short8*)&xt[ldsoA[4]] = v4;
    *(short8*)&xt[ldsoA[5]] = v5;
  }
  __syncthreads();
  kloop(aggb + (size_t)(b*2+1)*9216 + n*32 + kq*8);

  // epilogue: scale/bias + fast GELU (sigmoid-form tanh approx), fp32 stores
  #pragma unroll
  for (int tt = 0; tt < 2; ++tt){
    int lr = (tt == 0) ? lr0 : lr1;
    int p = p0 + lr, q = q0 + qb;
    #pragma unroll
    for (int r = 0; r < 16; ++r){
      int o = (r & 3) + 8*(r >> 2) + 4*kq;
      float v = acc[tt][r]*sSs[o] + tTs[o];
      float z = v * fmaf(0.0713548163f, v*v, 1.5957691216f);  // 2*0.79788456*(1+0.044715 v^2)
      float gl = v / (1.0f + __expf(-z));                      // v * sigmoid(z)
      out[(((size_t)(b*32+o)) << 16) + (p << 8) + q] = gl;
    }
  }
}

extern "C" void kernel_launch(void* const* d_in, const int* in_sizes, int n_in,
                              void* d_out, int out_size, void* d_ws, size_t ws_size,
                              hipStream_t stream)
{
  const float* x     = (const float*)d_in[0];
  const float* fc_w  = (const float*)d_in[1];
  const float* bga   = (const float*)d_in[2];
  const float* bba   = (const float*)d_in[3];
  const float* bma   = (const float*)d_in[4];
  const float* bva   = (const float*)d_in[5];
  const float* ch_w  = (const float*)d_in[6];
  const float* ch_b  = (const float*)d_in[7];
  const float* fil_w = (const float*)d_in[8];
  const float* fil_b = (const float*)d_in[9];
  const float* sp_w  = (const float*)d_in[10];
  const float* sp_b  = (const float*)d_in[11];
  const float* k_w   = (const float*)d_in[12];
  const float* k_b   = (const float*)d_in[13];
  const float* weight= (const float*)d_in[14];
  const float* bn_g  = (const float*)d_in[15];
  const float* bn_b  = (const float*)d_in[16];
  const float* bn_m  = (const float*)d_in[17];
  const float* bn_v  = (const float*)d_in[18];

  char* ws = (char*)d_ws;
  float* g   = (float*)(ws + WS_G);
  float* sS  = (float*)(ws + WS_S);
  float* tT  = (float*)(ws + WS_T);
  unsigned short* aggb = (unsigned short*)(ws + WS_AGGB);
  unsigned short* xup  = (unsigned short*)(ws + WS_XUP);
  float* out = (float*)d_out;

  hipMemsetAsync(g, 0, 512*sizeof(float), stream);
  hipLaunchKernelGGL(k_up,   dim3(2048), dim3(256), 0, stream, x, (unsigned int*)xup, g);
  hipLaunchKernelGGL(k_aggw, dim3(576),  dim3(256), 0, stream, g, fc_w, bga, bba, bma, bva,
                     ch_w, ch_b, fil_w, fil_b, sp_w, sp_b, k_w, k_b,
                     bn_g, bn_b, bn_m, bn_v, weight, aggb, sS, tT);
  hipLaunchKernelGGL(k_conv, dim3(2048), dim3(256), 0, stream, xup, aggb, sS, tT, out);
}

// Round 12
// 186.377 us; speedup vs baseline: 1.0079x; 1.0079x over previous
//
#include <hip/hip_runtime.h>
#include <hip/hip_bf16.h>

#define EPSBN 1e-5f

typedef short short8 __attribute__((ext_vector_type(8)));
typedef float f32x16 __attribute__((ext_vector_type(16)));

static __device__ __forceinline__ unsigned short f2u(float f){
  __hip_bfloat16 h = __float2bfloat16(f);
  union { __hip_bfloat16 h; unsigned short u; } c; c.h = h; return c.u;
}

// ---- workspace layout (bytes) ----
#define WS_G     2048
#define WS_S     7168
#define WS_T     8192
#define WS_AGGB  16384      // 147456 bf16  [b][cc2][s9][o32][ci32]
#define WS_XUP   327680     // 33554432 bf16 [b][h16(4)][r256][c256][ci16]  (plane = 1<<20 halfwords)

#define XIN_S 820   // per-ci-plane float stride; 820%32=20 -> ci2 lanes (planes 2ci2)
                    // land on banks {0,8,16,24}: conflict-free column reads.

// ------- K1: bilinear x2 upsample -> bf16 planes, GAP fused -------
// 8-ci blocks. grid 2048 = b(8) x g8(8 ci-octets) x strip(32 of 8 rows).
// LDS 26.2KB -> 6 blocks/CU. XCD-chunked swizzle: b == xcd so xup writes land
// in the L2 slice k_conv (b==xcd) reads.
__global__ __launch_bounds__(256) void k_up(const float* __restrict__ x,
                                            unsigned int* __restrict__ xup32,
                                            float* __restrict__ g)
{
  __shared__ float xin[8*XIN_S];   // [ci8][ir6][j136: 128 data + 8 zero pad]
  __shared__ float w[128];
  int tid = threadIdx.x;
  int bi  = blockIdx.x;
  int sw  = ((bi & 7) << 8) + (bi >> 3);   // nwg=2048 bijective; b == xcd
  int b   = sw >> 8, rest = sw & 255;
  int g8  = rest >> 5, strip = rest & 31;
  int r0 = strip * 8;
  int i0b = (int)((float)r0 * (127.0f/255.0f));

  if (tid < 128){
    int i = tid;
    float s = 0.f;
    int rstart = max(0, (int)floorf((float)(i-1)*(255.0f/127.0f)));
    #pragma unroll
    for (int k = 0; k < 8; ++k){
      int r = rstart + k;
      if (r <= 255){
        float pos = (float)r * (127.0f/255.0f);
        int i0 = (int)pos; float fr = pos - (float)i0; int i1 = min(i0+1,127);
        if (i0 == i) s += 1.0f - fr;
        if (i1 == i) s += fr;
      }
    }
    w[i] = s;
  }
  // loads: 8 ci x 6 rows x 128 cols = 1536 float4, 6 per thread
  #pragma unroll
  for (int k = 0; k < 6; ++k){
    int e4 = tid + (k << 8);
    int j4 = e4 & 31, ci = (e4 >> 5) & 7, ir = e4 >> 8;
    int row = min(i0b + ir, 127);
    *(float4*)&xin[ci*XIN_S + ir*136 + j4*4] =
      *(const float4*)&x[(((size_t)(b*64 + g8*8 + ci)) << 14) + (row << 7) + j4*4];
  }
  // zero pad cols 128..135 (j0+1 clamp-free)
  for (int e2 = tid; e2 < 384; e2 += 256){
    int k = e2 & 7, t8 = e2 >> 3;
    int ir = t8 % 6, ci = t8 / 6;
    xin[ci*XIN_S + ir*136 + 128 + k] = 0.f;
  }
  __syncthreads();

  // ---- GAP partial: source rows 4*strip..4*strip+3 (disjoint across strips) ----
  {
    int ci_l = tid >> 5, kk = tid & 31;    // 8 ci x 32 lanes, 4 cols each
    float s = 0.f;
    const float* base = &xin[ci_l*XIN_S];
    #pragma unroll
    for (int row = 0; row < 4; ++row){
      int grow = 4*strip + row;
      int ir = grow - i0b;                 // in [0,6) by construction
      const float* rp = base + ir*136 + kk*4;
      float ss = 0.f;
      #pragma unroll
      for (int j = 0; j < 4; ++j) ss += rp[j]*w[kk*4+j];
      s += w[grow]*ss;
    }
    s += __shfl_down(s, 16, 32);
    s += __shfl_down(s, 8, 32);
    s += __shfl_down(s, 4, 32);
    s += __shfl_down(s, 2, 32);
    s += __shfl_down(s, 1, 32);
    if (kk == 0) atomicAdd(&g[b*64 + g8*8 + ci_l], s*(1.0f/65536.0f));
  }

  // ---- interp: horizontal-first, rolling 2-row register cache ----
  int ci2 = tid & 3, cbase = tid >> 2;     // cbase 0..63; c = cbase + 64*jj
  const float* b0p = &xin[(ci2*2+0)*XIN_S];
  const float* b1p = &xin[(ci2*2+1)*XIN_S];
  size_t plane32 = ((size_t)(b*4 + (g8 >> 1))) << 19;
  int slot = (g8 & 1)*4 + ci2;             // dword slot within [ci16] (8 dwords)

  #pragma unroll
  for (int jj = 0; jj < 4; ++jj){
    int c = cbase + 64*jj;
    float pos = (float)c * (127.0f/255.0f);
    int j0 = (int)pos; float ww = pos - (float)j0;

    int irA = 0;
    float A0, B0, A1, B1;
    {
      float x0 = b0p[j0],     x1 = b0p[j0+1];     A0 = x0 + (x1-x0)*ww;
      float y0 = b1p[j0],     y1 = b1p[j0+1];     A1 = y0 + (y1-y0)*ww;
      float x2 = b0p[136+j0], x3 = b0p[136+j0+1]; B0 = x2 + (x3-x2)*ww;
      float y2 = b1p[136+j0], y3 = b1p[136+j0+1]; B1 = y2 + (y3-y2)*ww;
    }
    #pragma unroll
    for (int rr = 0; rr < 8; ++rr){
      int r = r0 + rr;
      float posr = (float)r * (127.0f/255.0f);
      int i0 = (int)posr; float wh = posr - (float)i0;
      int ir0 = i0 - i0b;
      if (ir0 > irA){                 // wave-uniform branch (all threads share strip)
        A0 = B0; A1 = B1;
        int irB = ir0 + 1;            // <= 5 by construction
        float x0 = b0p[irB*136+j0], x1 = b0p[irB*136+j0+1]; B0 = x0 + (x1-x0)*ww;
        float y0 = b1p[irB*136+j0], y1 = b1p[irB*136+j0+1]; B1 = y0 + (y1-y0)*ww;
        irA = ir0;
      }
      float r0v = A0 + (B0-A0)*wh;
      float r1v = A1 + (B1-A1)*wh;
      unsigned pack = (unsigned)f2u(r0v) | (((unsigned)f2u(r1v)) << 16);
      xup32[plane32 + (size_t)(r*256 + c)*8 + slot] = pack;
    }
  }
}

// ------- K2: attention MLP (redundant per block) + aggregated bf16 filters -------
__global__ __launch_bounds__(256) void k_aggw(const float* __restrict__ g,
                      const float* __restrict__ fc_w,
                      const float* __restrict__ bga, const float* __restrict__ bba,
                      const float* __restrict__ bma, const float* __restrict__ bva,
                      const float* __restrict__ ch_w, const float* __restrict__ ch_b,
                      const float* __restrict__ fil_w, const float* __restrict__ fil_b,
                      const float* __restrict__ sp_w, const float* __restrict__ sp_b,
                      const float* __restrict__ k_w, const float* __restrict__ k_b,
                      const float* __restrict__ bn_g, const float* __restrict__ bn_b,
                      const float* __restrict__ bn_m, const float* __restrict__ bn_v,
                      const float* __restrict__ weight,
                      unsigned short* __restrict__ aggb,
                      float* __restrict__ sS, float* __restrict__ tT)
{
  __shared__ float h[8][16];
  int tid = threadIdx.x;
  if (tid < 128){
    int b = tid >> 4, a = tid & 15;
    float acc = 0.f;
    for (int c = 0; c < 64; ++c) acc += g[b*64+c] * fc_w[a*64+c];
    float v = (acc - bma[a]) * rsqrtf(bva[a] + EPSBN) * bga[a] + bba[a];
    h[b][a] = fmaxf(v, 0.f);
  }
  __syncthreads();

  int idx = blockIdx.x*256 + tid;
  int ci_l = idx & 31;
  int o    = (idx >> 5) & 31;
  int s    = (idx >> 10) % 9;
  int t2   = (idx >> 10) / 9;
  int cc   = t2 & 1, b = t2 >> 1;
  int ci   = cc*32 + ci_l;

  const float* hb = h[b];
  float zc = ch_b[ci], zs = sp_b[s];
  float z0 = k_b[0],  z1 = k_b[1];
  #pragma unroll
  for (int a = 0; a < 16; ++a){
    float hv = hb[a];
    zc += hv*ch_w[ci*16+a];
    zs += hv*sp_w[s*16+a];
    z0 += hv*k_w[a];
    z1 += hv*k_w[16+a];
  }
  float chv = 1.f/(1.f+expf(-zc));
  float spv = 1.f/(1.f+expf(-zs));
  float m = fmaxf(z0,z1);
  float e0 = expf(z0-m), e1 = expf(z1-m), inv = 1.f/(e0+e1);
  float ka0 = e0*inv, ka1 = e1*inv;
  float w0 = weight[(o*64+ci)*9+s];
  float w1 = weight[((32+o)*64+ci)*9+s];
  aggb[idx] = f2u(chv*spv*(ka0*w0 + ka1*w1));

  if (blockIdx.x == 0){
    int bb = tid >> 5, oo = tid & 31;
    float z = fil_b[oo];
    #pragma unroll
    for (int a = 0; a < 16; ++a) z += h[bb][a]*fil_w[oo*16+a];
    float f = 1.f/(1.f+expf(-z));
    float invs = rsqrtf(bn_v[oo] + EPSBN);
    sS[tid] = f * bn_g[oo] * invs;
    if (bb == 0) tT[oo] = bn_b[oo] - bn_m[oo]*bn_g[oo]*invs;
  }
}

// -------- K3: MFMA implicit-GEMM conv + BN + GELU --------
// EXACT R9 layout (best measured 47.3us): 16x16 px tile, 4 waves x 2 acc tiles,
// XT_STRIDE=40 plain addressing, 25.9KB LDS -> 6 blocks/CU, grid 2048, XCD
// swizzle, depth-2 A-pipeline, cc=1 staged post-kloop1 via cached descriptors,
// no launch-bounds cap (VGPR 60). R11's XOR-swizzle REVERTED (cost VALU+16 VGPR,
// only -25% conflicts, +3us). Only change kept from R11: fast sigmoid-form GELU
// epilogue (~250 VALU vs ~600 for erff; absmax identical, proven R11).
#define XT_STRIDE 40   // 32 ci + 8 pad halfwords (80 B, 16B-aligned, bank-balanced)

__global__ __launch_bounds__(256) void k_conv(const unsigned short* __restrict__ xup,
                                              const unsigned short* __restrict__ aggb,
                                              const float* __restrict__ sS,
                                              const float* __restrict__ tT,
                                              float* __restrict__ out)
{
  __shared__ unsigned short xt[18*18*XT_STRIDE];   // 25920 B
  __shared__ float sSs[32], tTs[32];

  int tid = threadIdx.x;
  int bi  = blockIdx.x;
  int sw  = ((bi & 7) << 8) + (bi >> 3);   // nwg=2048 -> xcd*256 + idx (bijective; b == xcd)
  int b   = sw >> 8, t = sw & 255;
  int p0  = (t >> 4) * 16, q0 = (t & 15) * 16;
  int lane = tid & 63, wv = tid >> 6;
  if (tid < 32){ sSs[tid] = sS[b*32+tid]; tTs[tid] = tT[tid]; }

  f32x16 acc[2];
  #pragma unroll
  for (int i = 0; i < 16; ++i){ acc[0][i] = 0.f; acc[1][i] = 0.f; }

  int n  = lane & 31;
  int kq = lane >> 5;
  int lr0 = 2*(2*wv + 0) + (n >> 4);
  int lr1 = 2*(2*wv + 1) + (n >> 4);
  int qb  = n & 15;

  const unsigned short* xb0 = xup + (((size_t)(b*4 + 0)) << 20);
  const unsigned short* xb1 = xup + (((size_t)(b*4 + 2)) << 20);
  const short8 zero8 = {0,0,0,0,0,0,0,0};

  // ---- descriptors computed ONCE; both pmo and ldso cached for the cc=1 restage ----
  int ldsoA[6], pmoA[6];
  unsigned vmask = 0;
  #pragma unroll
  for (int k = 0; k < 6; ++k){
    int e = tid + (k << 8); if (e >= 1296) e -= 1296;   // wrap dupes benign
    int rr = e / 72; int rem = e - rr*72;
    int qq = rem >> 2; int k2 = (rem >> 1) & 1; int kqe = rem & 1;
    int gr = p0 - 1 + rr, gq = q0 - 1 + qq;
    bool v = ((unsigned)gr < 256u) && ((unsigned)gq < 256u);
    int ldso = (rr*18 + qq)*XT_STRIDE + k2*16 + kqe*8;
    int pmo  = (k2 << 20) + (gr*256 + gq)*16 + kqe*8;
    ldsoA[k] = ldso;
    pmoA[k]  = pmo;
    vmask |= (v ? 1u : 0u) << k;
    short8 vv = zero8;
    if (v) vv = *(const short8*)&xb0[pmo];
    *(short8*)&xt[ldso] = vv;
  }
  __syncthreads();

  // K-loop over a cc chunk; A-fragments pipelined 2 s-steps ahead
  auto kloop = [&](const unsigned short* ab){
    short8 a0 = *(const short8*)&ab[0];
    short8 a1 = *(const short8*)&ab[16];
    short8 b0 = *(const short8*)&ab[1024];
    short8 b1 = *(const short8*)&ab[1024+16];
    #pragma unroll
    for (int s = 0; s < 9; ++s){
      int sn = (s < 7) ? s+2 : 8;
      short8 c0 = *(const short8*)&ab[sn*1024];
      short8 c1 = *(const short8*)&ab[sn*1024+16];
      const int ky = s/3, kx = s%3;
      {
        const unsigned short* xrow = &xt[((lr0+ky)*18 + qb+kx)*XT_STRIDE + kq*8];
        short8 bv0 = *(const short8*)&xrow[0];
        short8 bv1 = *(const short8*)&xrow[16];
        acc[0] = __builtin_amdgcn_mfma_f32_32x32x16_bf16(a0, bv0, acc[0], 0, 0, 0);
        acc[0] = __builtin_amdgcn_mfma_f32_32x32x16_bf16(a1, bv1, acc[0], 0, 0, 0);
      }
      {
        const unsigned short* xrow = &xt[((lr1+ky)*18 + qb+kx)*XT_STRIDE + kq*8];
        short8 bv0 = *(const short8*)&xrow[0];
        short8 bv1 = *(const short8*)&xrow[16];
        acc[1] = __builtin_amdgcn_mfma_f32_32x32x16_bf16(a0, bv0, acc[1], 0, 0, 0);
        acc[1] = __builtin_amdgcn_mfma_f32_32x32x16_bf16(a1, bv1, acc[1], 0, 0, 0);
      }
      a0 = b0; a1 = b1; b0 = c0; b1 = c1;
    }
  };

  kloop(aggb + (size_t)(b*2+0)*9216 + n*32 + kq*8);
  __syncthreads();
  // stage cc=1 directly (cached descriptors; loads first, then LDS writes)
  {
    short8 v0 = zero8, v1 = zero8, v2 = zero8, v3 = zero8, v4 = zero8, v5 = zero8;
    if (vmask & 1u)  v0 = *(const short8*)&xb1[pmoA[0]];
    if (vmask & 2u)  v1 = *(const short8*)&xb1[pmoA[1]];
    if (vmask & 4u)  v2 = *(const short8*)&xb1[pmoA[2]];
    if (vmask & 8u)  v3 = *(const short8*)&xb1[pmoA[3]];
    if (vmask & 16u) v4 = *(const short8*)&xb1[pmoA[4]];
    if (vmask & 32u) v5 = *(const short8*)&xb1[pmoA[5]];
    *(short8*)&xt[ldsoA[0]] = v0;
    *(short8*)&xt[ldsoA[1]] = v1;
    *(short8*)&xt[ldsoA[2]] = v2;
    *(short8*)&xt[ldsoA[3]] = v3;
    *(short8*)&xt[ldsoA[4]] = v4;
    *(short8*)&xt[ldsoA[5]] = v5;
  }
  __syncthreads();
  kloop(aggb + (size_t)(b*2+1)*9216 + n*32 + kq*8);

  // epilogue: scale/bias + fast GELU (sigmoid-form tanh approx), fp32 stores
  #pragma unroll
  for (int tt = 0; tt < 2; ++tt){
    int lr = (tt == 0) ? lr0 : lr1;
    int p = p0 + lr, q = q0 + qb;
    #pragma unroll
    for (int r = 0; r < 16; ++r){
      int o = (r & 3) + 8*(r >> 2) + 4*kq;
      float v = acc[tt][r]*sSs[o] + tTs[o];
      float z = v * fmaf(0.0713548163f, v*v, 1.5957691216f);  // 2*0.79788456*(1+0.044715 v^2)
      float gl = v / (1.0f + __expf(-z));                      // v * sigmoid(z)
      out[(((size_t)(b*32+o)) << 16) + (p << 8) + q] = gl;
    }
  }
}

extern "C" void kernel_launch(void* const* d_in, const int* in_sizes, int n_in,
                              void* d_out, int out_size, void* d_ws, size_t ws_size,
                              hipStream_t stream)
{
  const float* x     = (const float*)d_in[0];
  const float* fc_w  = (const float*)d_in[1];
  const float* bga   = (const float*)d_in[2];
  const float* bba   = (const float*)d_in[3];
  const float* bma   = (const float*)d_in[4];
  const float* bva   = (const float*)d_in[5];
  const float* ch_w  = (const float*)d_in[6];
  const float* ch_b  = (const float*)d_in[7];
  const float* fil_w = (const float*)d_in[8];
  const float* fil_b = (const float*)d_in[9];
  const float* sp_w  = (const float*)d_in[10];
  const float* sp_b  = (const float*)d_in[11];
  const float* k_w   = (const float*)d_in[12];
  const float* k_b   = (const float*)d_in[13];
  const float* weight= (const float*)d_in[14];
  const float* bn_g  = (const float*)d_in[15];
  const float* bn_b  = (const float*)d_in[16];
  const float* bn_m  = (const float*)d_in[17];
  const float* bn_v  = (const float*)d_in[18];

  char* ws = (char*)d_ws;
  float* g   = (float*)(ws + WS_G);
  float* sS  = (float*)(ws + WS_S);
  float* tT  = (float*)(ws + WS_T);
  unsigned short* aggb = (unsigned short*)(ws + WS_AGGB);
  unsigned short* xup  = (unsigned short*)(ws + WS_XUP);
  float* out = (float*)d_out;

  hipMemsetAsync(g, 0, 512*sizeof(float), stream);
  hipLaunchKernelGGL(k_up,   dim3(2048), dim3(256), 0, stream, x, (unsigned int*)xup, g);
  hipLaunchKernelGGL(k_aggw, dim3(576),  dim3(256), 0, stream, g, fc_w, bga, bba, bma, bva,
                     ch_w, ch_b, fil_w, fil_b, sp_w, sp_b, k_w, k_b,
                     bn_g, bn_b, bn_m, bn_v, weight, aggb, sS, tT);
  hipLaunchKernelGGL(k_conv, dim3(2048), dim3(256), 0, stream, xup, aggb, sS, tT, out);
}

// Round 13
// 183.760 us; speedup vs baseline: 1.0222x; 1.0142x over previous
//
#include <hip/hip_runtime.h>
#include <hip/hip_bf16.h>

#define EPSBN 1e-5f

typedef short short8 __attribute__((ext_vector_type(8)));
typedef float f32x16 __attribute__((ext_vector_type(16)));

static __device__ __forceinline__ unsigned short f2u(float f){
  __hip_bfloat16 h = __float2bfloat16(f);
  union { __hip_bfloat16 h; unsigned short u; } c; c.h = h; return c.u;
}

// ---- workspace layout (bytes) ----
#define WS_G     2048
#define WS_S     7168
#define WS_T     8192
#define WS_AGGB  16384      // 147456 bf16  [b][cc2][s9][o32][ci32]
#define WS_XUP   327680     // 33554432 bf16 [b][h16(4)][r256][c256][ci16]  (plane = 1<<20 halfwords)

#define XIN_S 820   // per-ci-plane float stride; 820%32=20 -> ci2 lanes (planes 2ci2)
                    // land on banks {0,8,16,24}: conflict-free column reads.

// ------- K1: bilinear x2 upsample -> bf16 planes, GAP fused -------
// 8-ci blocks. grid 2048 = b(8) x g8(8 ci-octets) x strip(32 of 8 rows).
// LDS 26.2KB -> 6 blocks/CU. XCD-chunked swizzle: b == xcd so xup writes land
// in the L2 slice k_conv (b==xcd) reads.
__global__ __launch_bounds__(256) void k_up(const float* __restrict__ x,
                                            unsigned int* __restrict__ xup32,
                                            float* __restrict__ g)
{
  __shared__ float xin[8*XIN_S];   // [ci8][ir6][j136: 128 data + 8 zero pad]
  __shared__ float w[128];
  int tid = threadIdx.x;
  int bi  = blockIdx.x;
  int sw  = ((bi & 7) << 8) + (bi >> 3);   // nwg=2048 bijective; b == xcd
  int b   = sw >> 8, rest = sw & 255;
  int g8  = rest >> 5, strip = rest & 31;
  int r0 = strip * 8;
  int i0b = (int)((float)r0 * (127.0f/255.0f));

  if (tid < 128){
    int i = tid;
    float s = 0.f;
    int rstart = max(0, (int)floorf((float)(i-1)*(255.0f/127.0f)));
    #pragma unroll
    for (int k = 0; k < 8; ++k){
      int r = rstart + k;
      if (r <= 255){
        float pos = (float)r * (127.0f/255.0f);
        int i0 = (int)pos; float fr = pos - (float)i0; int i1 = min(i0+1,127);
        if (i0 == i) s += 1.0f - fr;
        if (i1 == i) s += fr;
      }
    }
    w[i] = s;
  }
  // loads: 8 ci x 6 rows x 128 cols = 1536 float4, 6 per thread
  #pragma unroll
  for (int k = 0; k < 6; ++k){
    int e4 = tid + (k << 8);
    int j4 = e4 & 31, ci = (e4 >> 5) & 7, ir = e4 >> 8;
    int row = min(i0b + ir, 127);
    *(float4*)&xin[ci*XIN_S + ir*136 + j4*4] =
      *(const float4*)&x[(((size_t)(b*64 + g8*8 + ci)) << 14) + (row << 7) + j4*4];
  }
  // zero pad cols 128..135 (j0+1 clamp-free)
  for (int e2 = tid; e2 < 384; e2 += 256){
    int k = e2 & 7, t8 = e2 >> 3;
    int ir = t8 % 6, ci = t8 / 6;
    xin[ci*XIN_S + ir*136 + 128 + k] = 0.f;
  }
  __syncthreads();

  // ---- GAP partial: source rows 4*strip..4*strip+3 (disjoint across strips) ----
  {
    int ci_l = tid >> 5, kk = tid & 31;    // 8 ci x 32 lanes, 4 cols each
    float s = 0.f;
    const float* base = &xin[ci_l*XIN_S];
    #pragma unroll
    for (int row = 0; row < 4; ++row){
      int grow = 4*strip + row;
      int ir = grow - i0b;                 // in [0,6) by construction
      const float* rp = base + ir*136 + kk*4;
      float ss = 0.f;
      #pragma unroll
      for (int j = 0; j < 4; ++j) ss += rp[j]*w[kk*4+j];
      s += w[grow]*ss;
    }
    s += __shfl_down(s, 16, 32);
    s += __shfl_down(s, 8, 32);
    s += __shfl_down(s, 4, 32);
    s += __shfl_down(s, 2, 32);
    s += __shfl_down(s, 1, 32);
    if (kk == 0) atomicAdd(&g[b*64 + g8*8 + ci_l], s*(1.0f/65536.0f));
  }

  // ---- interp: horizontal-first, rolling 2-row register cache ----
  int ci2 = tid & 3, cbase = tid >> 2;     // cbase 0..63; c = cbase + 64*jj
  const float* b0p = &xin[(ci2*2+0)*XIN_S];
  const float* b1p = &xin[(ci2*2+1)*XIN_S];
  size_t plane32 = ((size_t)(b*4 + (g8 >> 1))) << 19;
  int slot = (g8 & 1)*4 + ci2;             // dword slot within [ci16] (8 dwords)

  #pragma unroll
  for (int jj = 0; jj < 4; ++jj){
    int c = cbase + 64*jj;
    float pos = (float)c * (127.0f/255.0f);
    int j0 = (int)pos; float ww = pos - (float)j0;

    int irA = 0;
    float A0, B0, A1, B1;
    {
      float x0 = b0p[j0],     x1 = b0p[j0+1];     A0 = x0 + (x1-x0)*ww;
      float y0 = b1p[j0],     y1 = b1p[j0+1];     A1 = y0 + (y1-y0)*ww;
      float x2 = b0p[136+j0], x3 = b0p[136+j0+1]; B0 = x2 + (x3-x2)*ww;
      float y2 = b1p[136+j0], y3 = b1p[136+j0+1]; B1 = y2 + (y3-y2)*ww;
    }
    #pragma unroll
    for (int rr = 0; rr < 8; ++rr){
      int r = r0 + rr;
      float posr = (float)r * (127.0f/255.0f);
      int i0 = (int)posr; float wh = posr - (float)i0;
      int ir0 = i0 - i0b;
      if (ir0 > irA){                 // wave-uniform branch (all threads share strip)
        A0 = B0; A1 = B1;
        int irB = ir0 + 1;            // <= 5 by construction
        float x0 = b0p[irB*136+j0], x1 = b0p[irB*136+j0+1]; B0 = x0 + (x1-x0)*ww;
        float y0 = b1p[irB*136+j0], y1 = b1p[irB*136+j0+1]; B1 = y0 + (y1-y0)*ww;
        irA = ir0;
      }
      float r0v = A0 + (B0-A0)*wh;
      float r1v = A1 + (B1-A1)*wh;
      unsigned pack = (unsigned)f2u(r0v) | (((unsigned)f2u(r1v)) << 16);
      xup32[plane32 + (size_t)(r*256 + c)*8 + slot] = pack;
    }
  }
}

// ------- K2: attention MLP (redundant per block) + aggregated bf16 filters -------
__global__ __launch_bounds__(256) void k_aggw(const float* __restrict__ g,
                      const float* __restrict__ fc_w,
                      const float* __restrict__ bga, const float* __restrict__ bba,
                      const float* __restrict__ bma, const float* __restrict__ bva,
                      const float* __restrict__ ch_w, const float* __restrict__ ch_b,
                      const float* __restrict__ fil_w, const float* __restrict__ fil_b,
                      const float* __restrict__ sp_w, const float* __restrict__ sp_b,
                      const float* __restrict__ k_w, const float* __restrict__ k_b,
                      const float* __restrict__ bn_g, const float* __restrict__ bn_b,
                      const float* __restrict__ bn_m, const float* __restrict__ bn_v,
                      const float* __restrict__ weight,
                      unsigned short* __restrict__ aggb,
                      float* __restrict__ sS, float* __restrict__ tT)
{
  __shared__ float h[8][16];
  int tid = threadIdx.x;
  if (tid < 128){
    int b = tid >> 4, a = tid & 15;
    float acc = 0.f;
    for (int c = 0; c < 64; ++c) acc += g[b*64+c] * fc_w[a*64+c];
    float v = (acc - bma[a]) * rsqrtf(bva[a] + EPSBN) * bga[a] + bba[a];
    h[b][a] = fmaxf(v, 0.f);
  }
  __syncthreads();

  int idx = blockIdx.x*256 + tid;
  int ci_l = idx & 31;
  int o    = (idx >> 5) & 31;
  int s    = (idx >> 10) % 9;
  int t2   = (idx >> 10) / 9;
  int cc   = t2 & 1, b = t2 >> 1;
  int ci   = cc*32 + ci_l;

  const float* hb = h[b];
  float zc = ch_b[ci], zs = sp_b[s];
  float z0 = k_b[0],  z1 = k_b[1];
  #pragma unroll
  for (int a = 0; a < 16; ++a){
    float hv = hb[a];
    zc += hv*ch_w[ci*16+a];
    zs += hv*sp_w[s*16+a];
    z0 += hv*k_w[a];
    z1 += hv*k_w[16+a];
  }
  float chv = 1.f/(1.f+expf(-zc));
  float spv = 1.f/(1.f+expf(-zs));
  float m = fmaxf(z0,z1);
  float e0 = expf(z0-m), e1 = expf(z1-m), inv = 1.f/(e0+e1);
  float ka0 = e0*inv, ka1 = e1*inv;
  float w0 = weight[(o*64+ci)*9+s];
  float w1 = weight[((32+o)*64+ci)*9+s];
  aggb[idx] = f2u(chv*spv*(ka0*w0 + ka1*w1));

  if (blockIdx.x == 0){
    int bb = tid >> 5, oo = tid & 31;
    float z = fil_b[oo];
    #pragma unroll
    for (int a = 0; a < 16; ++a) z += h[bb][a]*fil_w[oo*16+a];
    float f = 1.f/(1.f+expf(-z));
    float invs = rsqrtf(bn_v[oo] + EPSBN);
    sS[tid] = f * bn_g[oo] * invs;
    if (bb == 0) tT[oo] = bn_b[oo] - bn_m[oo]*bn_g[oo]*invs;
  }
}

// -------- K3: MFMA implicit-GEMM conv + BN + GELU --------
// EXACT R9 kernel (best measured 47.3us, 3x reproduced): 16x16 px tile, 4 waves
// x 2 acc tiles, XT_STRIDE=40 plain addressing, 25.9KB LDS -> 6 blocks/CU, grid
// 2048, XCD swizzle, depth-2 A-pipeline, cc=1 staged post-kloop1 via cached
// descriptors, erf epilogue. R12 lesson: the "fast GELU" epilogue lifted VGPR
// 60->72, crossing the 64-reg cliff (8->4 waves/SIMD) -> +3us. The erff epilogue
// compiles to VGPR 60 and its VALU cost is hidden under memory stalls at 8
// waves/SIMD. Occupancy tiers beat instruction counts in this kernel -- always.
#define XT_STRIDE 40   // 32 ci + 8 pad halfwords (80 B, 16B-aligned, bank-balanced)

__global__ __launch_bounds__(256) void k_conv(const unsigned short* __restrict__ xup,
                                              const unsigned short* __restrict__ aggb,
                                              const float* __restrict__ sS,
                                              const float* __restrict__ tT,
                                              float* __restrict__ out)
{
  __shared__ unsigned short xt[18*18*XT_STRIDE];   // 25920 B
  __shared__ float sSs[32], tTs[32];

  int tid = threadIdx.x;
  int bi  = blockIdx.x;
  int sw  = ((bi & 7) << 8) + (bi >> 3);   // nwg=2048 -> xcd*256 + idx (bijective; b == xcd)
  int b   = sw >> 8, t = sw & 255;
  int p0  = (t >> 4) * 16, q0 = (t & 15) * 16;
  int lane = tid & 63, wv = tid >> 6;
  if (tid < 32){ sSs[tid] = sS[b*32+tid]; tTs[tid] = tT[tid]; }

  f32x16 acc[2];
  #pragma unroll
  for (int i = 0; i < 16; ++i){ acc[0][i] = 0.f; acc[1][i] = 0.f; }

  int n  = lane & 31;
  int kq = lane >> 5;
  int lr0 = 2*(2*wv + 0) + (n >> 4);
  int lr1 = 2*(2*wv + 1) + (n >> 4);
  int qb  = n & 15;

  const unsigned short* xb0 = xup + (((size_t)(b*4 + 0)) << 20);
  const unsigned short* xb1 = xup + (((size_t)(b*4 + 2)) << 20);
  const short8 zero8 = {0,0,0,0,0,0,0,0};

  // ---- descriptors computed ONCE; both pmo and ldso cached for the cc=1 restage ----
  int ldsoA[6], pmoA[6];
  unsigned vmask = 0;
  #pragma unroll
  for (int k = 0; k < 6; ++k){
    int e = tid + (k << 8); if (e >= 1296) e -= 1296;   // wrap dupes benign
    int rr = e / 72; int rem = e - rr*72;
    int qq = rem >> 2; int k2 = (rem >> 1) & 1; int kqe = rem & 1;
    int gr = p0 - 1 + rr, gq = q0 - 1 + qq;
    bool v = ((unsigned)gr < 256u) && ((unsigned)gq < 256u);
    int ldso = (rr*18 + qq)*XT_STRIDE + k2*16 + kqe*8;
    int pmo  = (k2 << 20) + (gr*256 + gq)*16 + kqe*8;
    ldsoA[k] = ldso;
    pmoA[k]  = pmo;
    vmask |= (v ? 1u : 0u) << k;
    short8 vv = zero8;
    if (v) vv = *(const short8*)&xb0[pmo];
    *(short8*)&xt[ldso] = vv;
  }
  __syncthreads();

  // K-loop over a cc chunk; A-fragments pipelined 2 s-steps ahead
  auto kloop = [&](const unsigned short* ab){
    short8 a0 = *(const short8*)&ab[0];
    short8 a1 = *(const short8*)&ab[16];
    short8 b0 = *(const short8*)&ab[1024];
    short8 b1 = *(const short8*)&ab[1024+16];
    #pragma unroll
    for (int s = 0; s < 9; ++s){
      int sn = (s < 7) ? s+2 : 8;
      short8 c0 = *(const short8*)&ab[sn*1024];
      short8 c1 = *(const short8*)&ab[sn*1024+16];
      const int ky = s/3, kx = s%3;
      {
        const unsigned short* xrow = &xt[((lr0+ky)*18 + qb+kx)*XT_STRIDE + kq*8];
        short8 bv0 = *(const short8*)&xrow[0];
        short8 bv1 = *(const short8*)&xrow[16];
        acc[0] = __builtin_amdgcn_mfma_f32_32x32x16_bf16(a0, bv0, acc[0], 0, 0, 0);
        acc[0] = __builtin_amdgcn_mfma_f32_32x32x16_bf16(a1, bv1, acc[0], 0, 0, 0);
      }
      {
        const unsigned short* xrow = &xt[((lr1+ky)*18 + qb+kx)*XT_STRIDE + kq*8];
        short8 bv0 = *(const short8*)&xrow[0];
        short8 bv1 = *(const short8*)&xrow[16];
        acc[1] = __builtin_amdgcn_mfma_f32_32x32x16_bf16(a0, bv0, acc[1], 0, 0, 0);
        acc[1] = __builtin_amdgcn_mfma_f32_32x32x16_bf16(a1, bv1, acc[1], 0, 0, 0);
      }
      a0 = b0; a1 = b1; b0 = c0; b1 = c1;
    }
  };

  kloop(aggb + (size_t)(b*2+0)*9216 + n*32 + kq*8);
  __syncthreads();
  // stage cc=1 directly (cached descriptors; loads first, then LDS writes)
  {
    short8 v0 = zero8, v1 = zero8, v2 = zero8, v3 = zero8, v4 = zero8, v5 = zero8;
    if (vmask & 1u)  v0 = *(const short8*)&xb1[pmoA[0]];
    if (vmask & 2u)  v1 = *(const short8*)&xb1[pmoA[1]];
    if (vmask & 4u)  v2 = *(const short8*)&xb1[pmoA[2]];
    if (vmask & 8u)  v3 = *(const short8*)&xb1[pmoA[3]];
    if (vmask & 16u) v4 = *(const short8*)&xb1[pmoA[4]];
    if (vmask & 32u) v5 = *(const short8*)&xb1[pmoA[5]];
    *(short8*)&xt[ldsoA[0]] = v0;
    *(short8*)&xt[ldsoA[1]] = v1;
    *(short8*)&xt[ldsoA[2]] = v2;
    *(short8*)&xt[ldsoA[3]] = v3;
    *(short8*)&xt[ldsoA[4]] = v4;
    *(short8*)&xt[ldsoA[5]] = v5;
  }
  __syncthreads();
  kloop(aggb + (size_t)(b*2+1)*9216 + n*32 + kq*8);

  // epilogue: scale/bias + GELU(exact erf), fp32 stores
  #pragma unroll
  for (int tt = 0; tt < 2; ++tt){
    int lr = (tt == 0) ? lr0 : lr1;
    int p = p0 + lr, q = q0 + qb;
    #pragma unroll
    for (int r = 0; r < 16; ++r){
      int o = (r & 3) + 8*(r >> 2) + 4*kq;
      float valv = acc[tt][r]*sSs[o] + tTs[o];
      float gl  = 0.5f*valv*(1.f + erff(valv*0.70710678118f));
      out[(((size_t)(b*32+o)) << 16) + (p << 8) + q] = gl;
    }
  }
}

extern "C" void kernel_launch(void* const* d_in, const int* in_sizes, int n_in,
                              void* d_out, int out_size, void* d_ws, size_t ws_size,
                              hipStream_t stream)
{
  const float* x     = (const float*)d_in[0];
  const float* fc_w  = (const float*)d_in[1];
  const float* bga   = (const float*)d_in[2];
  const float* bba   = (const float*)d_in[3];
  const float* bma   = (const float*)d_in[4];
  const float* bva   = (const float*)d_in[5];
  const float* ch_w  = (const float*)d_in[6];
  const float* ch_b  = (const float*)d_in[7];
  const float* fil_w = (const float*)d_in[8];
  const float* fil_b = (const float*)d_in[9];
  const float* sp_w  = (const float*)d_in[10];
  const float* sp_b  = (const float*)d_in[11];
  const float* k_w   = (const float*)d_in[12];
  const float* k_b   = (const float*)d_in[13];
  const float* weight= (const float*)d_in[14];
  const float* bn_g  = (const float*)d_in[15];
  const float* bn_b  = (const float*)d_in[16];
  const float* bn_m  = (const float*)d_in[17];
  const float* bn_v  = (const float*)d_in[18];

  char* ws = (char*)d_ws;
  float* g   = (float*)(ws + WS_G);
  float* sS  = (float*)(ws + WS_S);
  float* tT  = (float*)(ws + WS_T);
  unsigned short* aggb = (unsigned short*)(ws + WS_AGGB);
  unsigned short* xup  = (unsigned short*)(ws + WS_XUP);
  float* out = (float*)d_out;

  hipMemsetAsync(g, 0, 512*sizeof(float), stream);
  hipLaunchKernelGGL(k_up,   dim3(2048), dim3(256), 0, stream, x, (unsigned int*)xup, g);
  hipLaunchKernelGGL(k_aggw, dim3(576),  dim3(256), 0, stream, g, fc_w, bga, bba, bma, bva,
                     ch_w, ch_b, fil_w, fil_b, sp_w, sp_b, k_w, k_b,
                     bn_g, bn_b, bn_m, bn_v, weight, aggb, sS, tT);
  hipLaunchKernelGGL(k_conv, dim3(2048), dim3(256), 0, stream, xup, aggb, sS, tT, out);
}

// Round 14
// 180.680 us; speedup vs baseline: 1.0397x; 1.0170x over previous
//
#include <hip/hip_runtime.h>
#include <hip/hip_bf16.h>

#define EPSBN 1e-5f

typedef short short8 __attribute__((ext_vector_type(8)));
typedef float f32x16 __attribute__((ext_vector_type(16)));

static __device__ __forceinline__ unsigned short f2u(float f){
  __hip_bfloat16 h = __float2bfloat16(f);
  union { __hip_bfloat16 h; unsigned short u; } c; c.h = h; return c.u;
}

// ---- workspace layout (bytes) ----
#define WS_G     2048
#define WS_S     7168
#define WS_T     8192
#define WS_AGGB  16384      // 147456 bf16  [b][cc2][s9][o32][ci32]
#define WS_XUP   327680     // 33554432 bf16 [b][h16(4)][r256][c256][ci16]  (plane = 1<<20 halfwords)

#define XIN_S 820   // per-ci-plane float stride; 820%32=20 -> ci2 lanes (planes 2ci2)
                    // land on banks {0,8,16,24}: conflict-free column reads.

// ------- K1: bilinear x2 upsample -> bf16 planes, GAP fused -------
// 8-ci blocks. grid 2048 = b(8) x g8(8 ci-octets) x strip(32 of 8 rows).
// LDS 26.2KB -> 6 blocks/CU. XCD-chunked swizzle: b == xcd so xup writes land
// in the L2 slice k_conv (b==xcd) reads.
__global__ __launch_bounds__(256) void k_up(const float* __restrict__ x,
                                            unsigned int* __restrict__ xup32,
                                            float* __restrict__ g)
{
  __shared__ float xin[8*XIN_S];   // [ci8][ir6][j136: 128 data + 8 zero pad]
  __shared__ float w[128];
  int tid = threadIdx.x;
  int bi  = blockIdx.x;
  int sw  = ((bi & 7) << 8) + (bi >> 3);   // nwg=2048 bijective; b == xcd
  int b   = sw >> 8, rest = sw & 255;
  int g8  = rest >> 5, strip = rest & 31;
  int r0 = strip * 8;
  int i0b = (int)((float)r0 * (127.0f/255.0f));

  if (tid < 128){
    int i = tid;
    float s = 0.f;
    int rstart = max(0, (int)floorf((float)(i-1)*(255.0f/127.0f)));
    #pragma unroll
    for (int k = 0; k < 8; ++k){
      int r = rstart + k;
      if (r <= 255){
        float pos = (float)r * (127.0f/255.0f);
        int i0 = (int)pos; float fr = pos - (float)i0; int i1 = min(i0+1,127);
        if (i0 == i) s += 1.0f - fr;
        if (i1 == i) s += fr;
      }
    }
    w[i] = s;
  }
  // loads: 8 ci x 6 rows x 128 cols = 1536 float4, 6 per thread
  #pragma unroll
  for (int k = 0; k < 6; ++k){
    int e4 = tid + (k << 8);
    int j4 = e4 & 31, ci = (e4 >> 5) & 7, ir = e4 >> 8;
    int row = min(i0b + ir, 127);
    *(float4*)&xin[ci*XIN_S + ir*136 + j4*4] =
      *(const float4*)&x[(((size_t)(b*64 + g8*8 + ci)) << 14) + (row << 7) + j4*4];
  }
  // zero pad cols 128..135 (j0+1 clamp-free)
  for (int e2 = tid; e2 < 384; e2 += 256){
    int k = e2 & 7, t8 = e2 >> 3;
    int ir = t8 % 6, ci = t8 / 6;
    xin[ci*XIN_S + ir*136 + 128 + k] = 0.f;
  }
  __syncthreads();

  // ---- GAP partial: source rows 4*strip..4*strip+3 (disjoint across strips) ----
  {
    int ci_l = tid >> 5, kk = tid & 31;    // 8 ci x 32 lanes, 4 cols each
    float s = 0.f;
    const float* base = &xin[ci_l*XIN_S];
    #pragma unroll
    for (int row = 0; row < 4; ++row){
      int grow = 4*strip + row;
      int ir = grow - i0b;                 // in [0,6) by construction
      const float* rp = base + ir*136 + kk*4;
      float ss = 0.f;
      #pragma unroll
      for (int j = 0; j < 4; ++j) ss += rp[j]*w[kk*4+j];
      s += w[grow]*ss;
    }
    s += __shfl_down(s, 16, 32);
    s += __shfl_down(s, 8, 32);
    s += __shfl_down(s, 4, 32);
    s += __shfl_down(s, 2, 32);
    s += __shfl_down(s, 1, 32);
    if (kk == 0) atomicAdd(&g[b*64 + g8*8 + ci_l], s*(1.0f/65536.0f));
  }

  // ---- interp: horizontal-first, rolling 2-row register cache ----
  int ci2 = tid & 3, cbase = tid >> 2;     // cbase 0..63; c = cbase + 64*jj
  const float* b0p = &xin[(ci2*2+0)*XIN_S];
  const float* b1p = &xin[(ci2*2+1)*XIN_S];
  size_t plane32 = ((size_t)(b*4 + (g8 >> 1))) << 19;
  int slot = (g8 & 1)*4 + ci2;             // dword slot within [ci16] (8 dwords)

  #pragma unroll
  for (int jj = 0; jj < 4; ++jj){
    int c = cbase + 64*jj;
    float pos = (float)c * (127.0f/255.0f);
    int j0 = (int)pos; float ww = pos - (float)j0;

    int irA = 0;
    float A0, B0, A1, B1;
    {
      float x0 = b0p[j0],     x1 = b0p[j0+1];     A0 = x0 + (x1-x0)*ww;
      float y0 = b1p[j0],     y1 = b1p[j0+1];     A1 = y0 + (y1-y0)*ww;
      float x2 = b0p[136+j0], x3 = b0p[136+j0+1]; B0 = x2 + (x3-x2)*ww;
      float y2 = b1p[136+j0], y3 = b1p[136+j0+1]; B1 = y2 + (y3-y2)*ww;
    }
    #pragma unroll
    for (int rr = 0; rr < 8; ++rr){
      int r = r0 + rr;
      float posr = (float)r * (127.0f/255.0f);
      int i0 = (int)posr; float wh = posr - (float)i0;
      int ir0 = i0 - i0b;
      if (ir0 > irA){                 // wave-uniform branch (all threads share strip)
        A0 = B0; A1 = B1;
        int irB = ir0 + 1;            // <= 5 by construction
        float x0 = b0p[irB*136+j0], x1 = b0p[irB*136+j0+1]; B0 = x0 + (x1-x0)*ww;
        float y0 = b1p[irB*136+j0], y1 = b1p[irB*136+j0+1]; B1 = y0 + (y1-y0)*ww;
        irA = ir0;
      }
      float r0v = A0 + (B0-A0)*wh;
      float r1v = A1 + (B1-A1)*wh;
      unsigned pack = (unsigned)f2u(r0v) | (((unsigned)f2u(r1v)) << 16);
      xup32[plane32 + (size_t)(r*256 + c)*8 + slot] = pack;
    }
  }
}

// ------- K2: attention MLP (redundant per block) + aggregated bf16 filters -------
__global__ __launch_bounds__(256) void k_aggw(const float* __restrict__ g,
                      const float* __restrict__ fc_w,
                      const float* __restrict__ bga, const float* __restrict__ bba,
                      const float* __restrict__ bma, const float* __restrict__ bva,
                      const float* __restrict__ ch_w, const float* __restrict__ ch_b,
                      const float* __restrict__ fil_w, const float* __restrict__ fil_b,
                      const float* __restrict__ sp_w, const float* __restrict__ sp_b,
                      const float* __restrict__ k_w, const float* __restrict__ k_b,
                      const float* __restrict__ bn_g, const float* __restrict__ bn_b,
                      const float* __restrict__ bn_m, const float* __restrict__ bn_v,
                      const float* __restrict__ weight,
                      unsigned short* __restrict__ aggb,
                      float* __restrict__ sS, float* __restrict__ tT)
{
  __shared__ float h[8][16];
  int tid = threadIdx.x;
  if (tid < 128){
    int b = tid >> 4, a = tid & 15;
    float acc = 0.f;
    for (int c = 0; c < 64; ++c) acc += g[b*64+c] * fc_w[a*64+c];
    float v = (acc - bma[a]) * rsqrtf(bva[a] + EPSBN) * bga[a] + bba[a];
    h[b][a] = fmaxf(v, 0.f);
  }
  __syncthreads();

  int idx = blockIdx.x*256 + tid;
  int ci_l = idx & 31;
  int o    = (idx >> 5) & 31;
  int s    = (idx >> 10) % 9;
  int t2   = (idx >> 10) / 9;
  int cc   = t2 & 1, b = t2 >> 1;
  int ci   = cc*32 + ci_l;

  const float* hb = h[b];
  float zc = ch_b[ci], zs = sp_b[s];
  float z0 = k_b[0],  z1 = k_b[1];
  #pragma unroll
  for (int a = 0; a < 16; ++a){
    float hv = hb[a];
    zc += hv*ch_w[ci*16+a];
    zs += hv*sp_w[s*16+a];
    z0 += hv*k_w[a];
    z1 += hv*k_w[16+a];
  }
  float chv = 1.f/(1.f+expf(-zc));
  float spv = 1.f/(1.f+expf(-zs));
  float m = fmaxf(z0,z1);
  float e0 = expf(z0-m), e1 = expf(z1-m), inv = 1.f/(e0+e1);
  float ka0 = e0*inv, ka1 = e1*inv;
  float w0 = weight[(o*64+ci)*9+s];
  float w1 = weight[((32+o)*64+ci)*9+s];
  aggb[idx] = f2u(chv*spv*(ka0*w0 + ka1*w1));

  if (blockIdx.x == 0){
    int bb = tid >> 5, oo = tid & 31;
    float z = fil_b[oo];
    #pragma unroll
    for (int a = 0; a < 16; ++a) z += h[bb][a]*fil_w[oo*16+a];
    float f = 1.f/(1.f+expf(-z));
    float invs = rsqrtf(bn_v[oo] + EPSBN);
    sS[tid] = f * bn_g[oo] * invs;
    if (bb == 0) tT[oo] = bn_b[oo] - bn_m[oo]*bn_g[oo]*invs;
  }
}

// -------- K3: MFMA implicit-GEMM conv + BN + GELU --------
// EXACT R9 kernel (best measured 47.3us at VGPR 60, 6 blocks/CU) + T5 setprio:
// kloop wrapped in s_setprio(1)/(0). Mechanism: 6 independent blocks/CU are at
// DIFFERENT phases (staging vs compute) -> CU scheduler favors MFMA-phase waves
// over other blocks' staging waves (m191 regime, not m190's 1-block lockstep).
// Cost: 2 SALU/kloop, zero VGPR/LDS -> occupancy invariants preserved.
// R13 note: identical code measured 63us with MfmaUtil*dur conserved -> clock
// throttle, not code. Prediction: reverts to ~47 on a healthy container.
#define XT_STRIDE 40   // 32 ci + 8 pad halfwords (80 B, 16B-aligned, bank-balanced)

__global__ __launch_bounds__(256) void k_conv(const unsigned short* __restrict__ xup,
                                              const unsigned short* __restrict__ aggb,
                                              const float* __restrict__ sS,
                                              const float* __restrict__ tT,
                                              float* __restrict__ out)
{
  __shared__ unsigned short xt[18*18*XT_STRIDE];   // 25920 B
  __shared__ float sSs[32], tTs[32];

  int tid = threadIdx.x;
  int bi  = blockIdx.x;
  int sw  = ((bi & 7) << 8) + (bi >> 3);   // nwg=2048 -> xcd*256 + idx (bijective; b == xcd)
  int b   = sw >> 8, t = sw & 255;
  int p0  = (t >> 4) * 16, q0 = (t & 15) * 16;
  int lane = tid & 63, wv = tid >> 6;
  if (tid < 32){ sSs[tid] = sS[b*32+tid]; tTs[tid] = tT[tid]; }

  f32x16 acc[2];
  #pragma unroll
  for (int i = 0; i < 16; ++i){ acc[0][i] = 0.f; acc[1][i] = 0.f; }

  int n  = lane & 31;
  int kq = lane >> 5;
  int lr0 = 2*(2*wv + 0) + (n >> 4);
  int lr1 = 2*(2*wv + 1) + (n >> 4);
  int qb  = n & 15;

  const unsigned short* xb0 = xup + (((size_t)(b*4 + 0)) << 20);
  const unsigned short* xb1 = xup + (((size_t)(b*4 + 2)) << 20);
  const short8 zero8 = {0,0,0,0,0,0,0,0};

  // ---- descriptors computed ONCE; both pmo and ldso cached for the cc=1 restage ----
  int ldsoA[6], pmoA[6];
  unsigned vmask = 0;
  #pragma unroll
  for (int k = 0; k < 6; ++k){
    int e = tid + (k << 8); if (e >= 1296) e -= 1296;   // wrap dupes benign
    int rr = e / 72; int rem = e - rr*72;
    int qq = rem >> 2; int k2 = (rem >> 1) & 1; int kqe = rem & 1;
    int gr = p0 - 1 + rr, gq = q0 - 1 + qq;
    bool v = ((unsigned)gr < 256u) && ((unsigned)gq < 256u);
    int ldso = (rr*18 + qq)*XT_STRIDE + k2*16 + kqe*8;
    int pmo  = (k2 << 20) + (gr*256 + gq)*16 + kqe*8;
    ldsoA[k] = ldso;
    pmoA[k]  = pmo;
    vmask |= (v ? 1u : 0u) << k;
    short8 vv = zero8;
    if (v) vv = *(const short8*)&xb0[pmo];
    *(short8*)&xt[ldso] = vv;
  }
  __syncthreads();

  // K-loop over a cc chunk; A-fragments pipelined 2 s-steps ahead.
  // setprio(1): favor this wave while it is in its MFMA-dense phase.
  auto kloop = [&](const unsigned short* ab){
    __builtin_amdgcn_s_setprio(1);
    short8 a0 = *(const short8*)&ab[0];
    short8 a1 = *(const short8*)&ab[16];
    short8 b0 = *(const short8*)&ab[1024];
    short8 b1 = *(const short8*)&ab[1024+16];
    #pragma unroll
    for (int s = 0; s < 9; ++s){
      int sn = (s < 7) ? s+2 : 8;
      short8 c0 = *(const short8*)&ab[sn*1024];
      short8 c1 = *(const short8*)&ab[sn*1024+16];
      const int ky = s/3, kx = s%3;
      {
        const unsigned short* xrow = &xt[((lr0+ky)*18 + qb+kx)*XT_STRIDE + kq*8];
        short8 bv0 = *(const short8*)&xrow[0];
        short8 bv1 = *(const short8*)&xrow[16];
        acc[0] = __builtin_amdgcn_mfma_f32_32x32x16_bf16(a0, bv0, acc[0], 0, 0, 0);
        acc[0] = __builtin_amdgcn_mfma_f32_32x32x16_bf16(a1, bv1, acc[0], 0, 0, 0);
      }
      {
        const unsigned short* xrow = &xt[((lr1+ky)*18 + qb+kx)*XT_STRIDE + kq*8];
        short8 bv0 = *(const short8*)&xrow[0];
        short8 bv1 = *(const short8*)&xrow[16];
        acc[1] = __builtin_amdgcn_mfma_f32_32x32x16_bf16(a0, bv0, acc[1], 0, 0, 0);
        acc[1] = __builtin_amdgcn_mfma_f32_32x32x16_bf16(a1, bv1, acc[1], 0, 0, 0);
      }
      a0 = b0; a1 = b1; b0 = c0; b1 = c1;
    }
    __builtin_amdgcn_s_setprio(0);
  };

  kloop(aggb + (size_t)(b*2+0)*9216 + n*32 + kq*8);
  __syncthreads();
  // stage cc=1 directly (cached descriptors; loads first, then LDS writes)
  {
    short8 v0 = zero8, v1 = zero8, v2 = zero8, v3 = zero8, v4 = zero8, v5 = zero8;
    if (vmask & 1u)  v0 = *(const short8*)&xb1[pmoA[0]];
    if (vmask & 2u)  v1 = *(const short8*)&xb1[pmoA[1]];
    if (vmask & 4u)  v2 = *(const short8*)&xb1[pmoA[2]];
    if (vmask & 8u)  v3 = *(const short8*)&xb1[pmoA[3]];
    if (vmask & 16u) v4 = *(const short8*)&xb1[pmoA[4]];
    if (vmask & 32u) v5 = *(const short8*)&xb1[pmoA[5]];
    *(short8*)&xt[ldsoA[0]] = v0;
    *(short8*)&xt[ldsoA[1]] = v1;
    *(short8*)&xt[ldsoA[2]] = v2;
    *(short8*)&xt[ldsoA[3]] = v3;
    *(short8*)&xt[ldsoA[4]] = v4;
    *(short8*)&xt[ldsoA[5]] = v5;
  }
  __syncthreads();
  kloop(aggb + (size_t)(b*2+1)*9216 + n*32 + kq*8);

  // epilogue: scale/bias + GELU(exact erf), fp32 stores
  #pragma unroll
  for (int tt = 0; tt < 2; ++tt){
    int lr = (tt == 0) ? lr0 : lr1;
    int p = p0 + lr, q = q0 + qb;
    #pragma unroll
    for (int r = 0; r < 16; ++r){
      int o = (r & 3) + 8*(r >> 2) + 4*kq;
      float valv = acc[tt][r]*sSs[o] + tTs[o];
      float gl  = 0.5f*valv*(1.f + erff(valv*0.70710678118f));
      out[(((size_t)(b*32+o)) << 16) + (p << 8) + q] = gl;
    }
  }
}

extern "C" void kernel_launch(void* const* d_in, const int* in_sizes, int n_in,
                              void* d_out, int out_size, void* d_ws, size_t ws_size,
                              hipStream_t stream)
{
  const float* x     = (const float*)d_in[0];
  const float* fc_w  = (const float*)d_in[1];
  const float* bga   = (const float*)d_in[2];
  const float* bba   = (const float*)d_in[3];
  const float* bma   = (const float*)d_in[4];
  const float* bva   = (const float*)d_in[5];
  const float* ch_w  = (const float*)d_in[6];
  const float* ch_b  = (const float*)d_in[7];
  const float* fil_w = (const float*)d_in[8];
  const float* fil_b = (const float*)d_in[9];
  const float* sp_w  = (const float*)d_in[10];
  const float* sp_b  = (const float*)d_in[11];
  const float* k_w   = (const float*)d_in[12];
  const float* k_b   = (const float*)d_in[13];
  const float* weight= (const float*)d_in[14];
  const float* bn_g  = (const float*)d_in[15];
  const float* bn_b  = (const float*)d_in[16];
  const float* bn_m  = (const float*)d_in[17];
  const float* bn_v  = (const float*)d_in[18];

  char* ws = (char*)d_ws;
  float* g   = (float*)(ws + WS_G);
  float* sS  = (float*)(ws + WS_S);
  float* tT  = (float*)(ws + WS_T);
  unsigned short* aggb = (unsigned short*)(ws + WS_AGGB);
  unsigned short* xup  = (unsigned short*)(ws + WS_XUP);
  float* out = (float*)d_out;

  hipMemsetAsync(g, 0, 512*sizeof(float), stream);
  hipLaunchKernelGGL(k_up,   dim3(2048), dim3(256), 0, stream, x, (unsigned int*)xup, g);
  hipLaunchKernelGGL(k_aggw, dim3(576),  dim3(256), 0, stream, g, fc_w, bga, bba, bma, bva,
                     ch_w, ch_b, fil_w, fil_b, sp_w, sp_b, k_w, k_b,
                     bn_g, bn_b, bn_m, bn_v, weight, aggb, sS, tT);
  hipLaunchKernelGGL(k_conv, dim3(2048), dim3(256), 0, stream, xup, aggb, sS, tT, out);
}